// Round 15
// baseline (213.250 us; speedup 1.0000x reference)
//
#include <hip/hip_runtime.h>

#define B_  256
#define T_  256
#define S_  20
#define U1  32
#define G1  128   // 4*U1
#define U2  24
#define G2  96    // 4*U2
#define NT  16    // 16-row t-tiles per sequence

typedef __attribute__((ext_vector_type(8))) short short8;   // 8 bf16 = 4 VGPRs
typedef __attribute__((ext_vector_type(4))) float f32x4;    // MFMA acc

// Raw-HW activations (v_exp_f32 = 2^x, pre-scaled by log2e). R7: 134->74us.
__device__ __forceinline__ float sigmoidf_(float x) {
    return __builtin_amdgcn_rcpf(1.0f + __builtin_amdgcn_exp2f(x * -1.44269504f));
}
__device__ __forceinline__ float tanhf_fast(float x) {   // 1 - 2/(1+e^{2x})
    return 1.0f - 2.0f * __builtin_amdgcn_rcpf(1.0f + __builtin_amdgcn_exp2f(x * 2.88539008f));
}

__device__ __forceinline__ unsigned short f2bf(float a) {
    unsigned int u = __float_as_uint(a);
    u += 0x7FFFu + ((u >> 16) & 1u);
    return (unsigned short)(u >> 16);
}
__device__ __forceinline__ unsigned int pack2bf(float a, float b) {
    unsigned int ua = __float_as_uint(a); ua += 0x7FFFu + ((ua >> 16) & 1u);
    unsigned int ub = __float_as_uint(b); ub += 0x7FFFu + ((ub >> 16) & 1u);
    return (ua >> 16) | (ub & 0xFFFF0000u);
}
union frag_u { short8 v; unsigned int u[4]; };
union h2x  { unsigned int u32; _Float16 h[2]; };

// FUSED, TWO SEQUENCES PER BLOCK (512 thr = 8 waves, ~109 KB LDS, 1 blk/CU).
// Insight (R8..R14 fit): consumer cost == ~5.5-6.5 cyc/instruction because a
// SINGLE wave on a SIMD exposes every instruction's ~4-6cyc latency. No
// chain surgery changed that regime. Fix: TWO consumer waves (two
// sequences' recurrences) on the SAME SIMD interleave and hide each other's
// latency (~2x issue efficiency). Waves 0 and 4 land on SIMD 0 (wave i ->
// SIMD i%4): they consume seq 0 / seq 1. Waves {1,3,6} produce seq-0 tiles,
// {2,5,7} seq-1 tiles (2 producers per SIMD 1-3), per-tile LDS flags.
// Consumer = lowest-inst-count form (R8 half-split: 48 FMA + 2 shfl_xor +
// 24 readlane + 1 ds_read_b32/step from unit-major P).
__global__ __attribute__((amdgpu_flat_work_group_size(512, 512)))
__attribute__((amdgpu_waves_per_eu(2, 2)))
void fused_kernel(
    const float* __restrict__ x,        // [B*T*S]
    const int*   __restrict__ lengths,  // [B]
    const float* __restrict__ Wi,       // [G1]
    const float* __restrict__ Ui,       // [U1*G1]
    const float* __restrict__ bi,       // [G1]
    const float* __restrict__ Wo,       // [U1*G2]
    const float* __restrict__ Uo,       // [U2*G2]
    const float* __restrict__ bo,       // [G2]
    const float* __restrict__ Wd,       // [U2]
    const float* __restrict__ bd,       // [1]
    float* __restrict__ out)            // [B]
{
    __shared__ __align__(16) _Float16      Pl[2][T_][G2];   // [s][t][u*4+g], 96 KB
    __shared__ __align__(16) unsigned short hbb[8][16][40]; // per-wave h tiles, 10 KB
    __shared__ unsigned int flags[2 * NT];
    const int tid  = threadIdx.x;
    const int w    = __builtin_amdgcn_readfirstlane(tid >> 6);   // wave 0..7
    const int lane = tid & 63;
    const int q    = lane >> 4;
    const int n    = lane & 15;

    if (tid < 2 * NT) flags[tid] = 0;
    __syncthreads();                             // only barrier: flag init

    // ---- one-time fragment/bias loads (all waves) ----
    frag_u Bui[8];
#pragma unroll
    for (int tt = 0; tt < 8; ++tt)
#pragma unroll
        for (int k2 = 0; k2 < 4; ++k2)
            Bui[tt].u[k2] = pack2bf(Ui[(8 * q + 2 * k2) * G1 + 16 * tt + n],
                                    Ui[(8 * q + 2 * k2 + 1) * G1 + 16 * tt + n]);
    frag_u Bwo[6];
#pragma unroll
    for (int tt = 0; tt < 6; ++tt)
#pragma unroll
        for (int k2 = 0; k2 < 4; ++k2)
            Bwo[tt].u[k2] = pack2bf(Wo[(8 * q + 2 * k2) * G2 + 16 * tt + n],
                                    Wo[(8 * q + 2 * k2 + 1) * G2 + 16 * tt + n]);
    float bi_l[8], Wi_l[8], bo_l[6];
#pragma unroll
    for (int tt = 0; tt < 8; ++tt) { bi_l[tt] = bi[16 * tt + n]; Wi_l[tt] = Wi[16 * tt + n]; }
#pragma unroll
    for (int tt = 0; tt < 6; ++tt) bo_l[tt] = bo[16 * tt + n];
    // P-store targets: col=16tt+n -> (g=col/24, u=col%24) -> offset u*4+g
    int pcol[6];
#pragma unroll
    for (int tt = 0; tt < 6; ++tt) {
        const int col = 16 * tt + n;
        const int g = col / 24;
        pcol[tt] = (col - 24 * g) * 4 + g;
    }

    // ---- worklists ----
    // consumers (w==0 -> seq0, w==4 -> seq1): produce only tile 0 of their seq.
    // producers: p = (w<4) ? w-1 : w-2 in 0..5; seq = p&1; tiles base+3i,
    // base = 1+(p>>1): per-seq pattern {1,4,7,10,13},{2,5,8,11,14},{3,6,9,12,15}.
    int ps, base, ntl;
    const bool consumer = (w == 0) || (w == 4);
    if (consumer) { ps = (w == 4); base = 0; ntl = 1; }
    else {
        const int p = (w < 4) ? (w - 1) : (w - 2);
        ps = p & 1; base = 1 + (p >> 1); ntl = 5;
    }
    const int bs  = blockIdx.x * 2 + ps;         // global sequence index
    const int len = lengths[bs];                 // >= 1

#pragma unroll 1
    for (int i = 0; i < ntl; ++i) {
        const int tile = base + 3 * i;
        const int wt0  = tile * 16;
        if (wt0 >= len) break;                   // increasing list: rest masked

        const float* xr = x + (size_t)(bs * T_ + wt0 + 4 * q) * S_;
        float c[2][4];
#pragma unroll
        for (int uh = 0; uh < 2; ++uh)
#pragma unroll
            for (int r = 0; r < 4; ++r) c[uh][r] = 0.0f;

        float xc[4];
#pragma unroll
        for (int r = 0; r < 4; ++r) xc[r] = xr[r * S_];

        // peeled s = 0 (h == 0: no MFMA)
        {
            f32x4 acc[8];
#pragma unroll
            for (int tt = 0; tt < 8; ++tt)
#pragma unroll
                for (int r = 0; r < 4; ++r)
                    acc[tt][r] = bi_l[tt] + xc[r] * Wi_l[tt];
#pragma unroll
            for (int uh = 0; uh < 2; ++uh)
#pragma unroll
                for (int r = 0; r < 4; ++r) {
                    const float iv = sigmoidf_(acc[0 + uh][r]);
                    const float fv = sigmoidf_(acc[2 + uh][r]);
                    const float gv = tanhf_fast(acc[4 + uh][r]);
                    const float ov = sigmoidf_(acc[6 + uh][r]);
                    c[uh][r] = fv * c[uh][r] + iv * gv;
                    hbb[w][4 * q + r][n + 16 * uh] = f2bf(ov * tanhf_fast(c[uh][r]));
                }
        }
#pragma unroll
        for (int r = 0; r < 4; ++r) xc[r] = xr[r * S_ + 1];

        // steady state s = 1..19
#pragma unroll 1
        for (int s = 1; s < S_; ++s) {
            const int sn = (s + 1 < S_) ? s + 1 : S_ - 1;
            float xnx[4];
#pragma unroll
            for (int r = 0; r < 4; ++r) xnx[r] = xr[r * S_ + sn];

            f32x4 acc[8];
#pragma unroll
            for (int tt = 0; tt < 8; ++tt)
#pragma unroll
                for (int r = 0; r < 4; ++r)
                    acc[tt][r] = bi_l[tt] + xc[r] * Wi_l[tt];

            const short8 A = *(const short8*)&hbb[w][n][8 * q];
#pragma unroll
            for (int tt = 0; tt < 8; ++tt)
                acc[tt] = __builtin_amdgcn_mfma_f32_16x16x32_bf16(A, Bui[tt].v, acc[tt], 0, 0, 0);

#pragma unroll
            for (int uh = 0; uh < 2; ++uh)
#pragma unroll
                for (int r = 0; r < 4; ++r) {
                    const float iv = sigmoidf_(acc[0 + uh][r]);
                    const float fv = sigmoidf_(acc[2 + uh][r]);
                    const float gv = tanhf_fast(acc[4 + uh][r]);
                    const float ov = sigmoidf_(acc[6 + uh][r]);
                    c[uh][r] = fv * c[uh][r] + iv * gv;
                    hbb[w][4 * q + r][n + 16 * uh] = f2bf(ov * tanhf_fast(c[uh][r]));
                }
#pragma unroll
            for (int r = 0; r < 4; ++r) xc[r] = xnx[r];
        }

        // P tile = bo + h @ Wo -> LDS, unit-major pair layout
        {
            const short8 A = *(const short8*)&hbb[w][n][8 * q];
            f32x4 accp[6];
#pragma unroll
            for (int tt = 0; tt < 6; ++tt) {
#pragma unroll
                for (int r = 0; r < 4; ++r) accp[tt][r] = bo_l[tt];
                accp[tt] = __builtin_amdgcn_mfma_f32_16x16x32_bf16(A, Bwo[tt].v, accp[tt], 0, 0, 0);
            }
#pragma unroll
            for (int r = 0; r < 4; ++r) {
                const int tr = wt0 + 4 * q + r;
#pragma unroll
                for (int tt = 0; tt < 6; ++tt)
                    Pl[ps][tr][pcol[tt]] = (_Float16)accp[tt][r];
            }
        }
        __hip_atomic_store(&flags[ps * NT + tile], 1u, __ATOMIC_RELEASE,
                           __HIP_MEMORY_SCOPE_WORKGROUP);
    }

    if (!consumer) return;                       // producers retire

    // ======== phase 2: outer LSTM + head (waves 0 & 4, both on SIMD 0) =====
    const int half = lane >> 5;                  // 0: gates i,f  1: gates g,o
    const int sub  = lane & 31;
    const int u    = (sub < U2) ? sub : U2 - 1;

    float wA[U2], wB[U2];                        // 48 weight VGPRs
#pragma unroll
    for (int k = 0; k < U2; ++k) {
        wA[k] = Uo[k * G2 + (2 * half) * U2 + u];
        wB[k] = Uo[k * G2 + (2 * half + 1) * U2 + u];
    }

    // one ds_read_b32 per step: my 2 gates of unit u (f16 pair)
    auto ld2 = [&](int t) -> float2 {
        h2x pp; pp.u32 = *reinterpret_cast<const unsigned int*>(&Pl[ps][t][4 * u + 2 * half]);
        return make_float2((float)pp.h[0], (float)pp.h[1]);
    };

    float cu, hu;
    {   // peeled t = 0 (h == 0, c == 0)
        const float2 r0 = ld2(0);                // tile 0 self-produced
        const float zA = r0.x, zB = r0.y;
        const float oA = __shfl_xor(zA, 32);
        const float oB = __shfl_xor(zB, 32);
        const float z_i = half ? oA : zA;
        const float z_g = half ? zA : oA;
        const float z_o = half ? zB : oB;
        const float ig = sigmoidf_(z_i);
        const float gg = tanhf_fast(z_g);
        const float og = sigmoidf_(z_o);
        cu = ig * gg;
        hu = og * tanhf_fast(cu);
    }

    int t = 1, tile = 0;
    int tend = (16 < len) ? 16 : len;
    float2 nxt = ld2((1 < len) ? 1 : 0);

#pragma unroll 1
    while (t < len) {
        // hot loop: rows t .. tend-2 (prefetch stays inside this tile)
#pragma unroll 1
        for (; t + 1 < tend; ++t) {
            const float2 pf = ld2(t + 1);        // in-tile prefetch (off-chain)

            float hk[U2];
#pragma unroll
            for (int k = 0; k < U2; ++k)
                hk[k] = __int_as_float(__builtin_amdgcn_readlane(__float_as_int(hu), k));

            float a0 = nxt.x, a1 = 0.0f, b0 = nxt.y, b1 = 0.0f;
#pragma unroll
            for (int k = 0; k < U2; k += 2) {    // 2 chains x depth 12
                a0 += hk[k]     * wA[k];     b0 += hk[k]     * wB[k];
                a1 += hk[k + 1] * wA[k + 1]; b1 += hk[k + 1] * wB[k + 1];
            }
            const float zA = a0 + a1;            // half0: z_i ; half1: z_g
            const float zB = b0 + b1;            // half0: z_f ; half1: z_o
            const float oA = __shfl_xor(zA, 32);
            const float oB = __shfl_xor(zB, 32);

            const float z_i = half ? oA : zA;
            const float z_f = half ? oB : zB;
            const float z_g = half ? zA : oA;
            const float z_o = half ? zB : oB;

            const float ig = sigmoidf_(z_i);
            const float fg = sigmoidf_(z_f);
            const float gg = tanhf_fast(z_g);
            const float og = sigmoidf_(z_o);
            cu = fg * cu + ig * gg;
            hu = og * tanhf_fast(cu);            // identical on both halves
            nxt = pf;
        }

        // boundary row t == tend-1: flag-wait + fetch next tile's first row
        float2 pf = nxt;
        if (tend < len) {                        // wave-uniform
            ++tile;
            while (__hip_atomic_load(&flags[ps * NT + tile], __ATOMIC_ACQUIRE,
                                     __HIP_MEMORY_SCOPE_WORKGROUP) == 0u)
                __builtin_amdgcn_s_sleep(1);
            pf = ld2(tend);
        }
        {
            float hk[U2];
#pragma unroll
            for (int k = 0; k < U2; ++k)
                hk[k] = __int_as_float(__builtin_amdgcn_readlane(__float_as_int(hu), k));

            float a0 = nxt.x, a1 = 0.0f, b0 = nxt.y, b1 = 0.0f;
#pragma unroll
            for (int k = 0; k < U2; k += 2) {
                a0 += hk[k]     * wA[k];     b0 += hk[k]     * wB[k];
                a1 += hk[k + 1] * wA[k + 1]; b1 += hk[k + 1] * wB[k + 1];
            }
            const float zA = a0 + a1;
            const float zB = b0 + b1;
            const float oA = __shfl_xor(zA, 32);
            const float oB = __shfl_xor(zB, 32);

            const float z_i = half ? oA : zA;
            const float z_f = half ? oB : zB;
            const float z_g = half ? zA : oA;
            const float z_o = half ? zB : oB;

            const float ig = sigmoidf_(z_i);
            const float fg = sigmoidf_(z_f);
            const float gg = tanhf_fast(z_g);
            const float og = sigmoidf_(z_o);
            cu = fg * cu + ig * gg;
            hu = og * tanhf_fast(cu);
        }
        ++t;
        nxt = pf;
        tend = (tend + 16 < len) ? tend + 16 : len;
    }

    // dense sigmoid head
    float acc = bd[0];
#pragma unroll
    for (int k = 0; k < U2; ++k)
        acc += __int_as_float(__builtin_amdgcn_readlane(__float_as_int(hu), k)) * Wd[k];
    if (lane == 0) out[bs] = sigmoidf_(acc);
}

extern "C" void kernel_launch(void* const* d_in, const int* in_sizes, int n_in,
                              void* d_out, int out_size, void* d_ws, size_t ws_size,
                              hipStream_t stream) {
    const float* x       = (const float*)d_in[0];
    const int*   lengths = (const int*)  d_in[1];
    const float* Wi      = (const float*)d_in[2];
    const float* Ui      = (const float*)d_in[3];
    const float* bi      = (const float*)d_in[4];
    const float* Wo      = (const float*)d_in[5];
    const float* Uo      = (const float*)d_in[6];
    const float* bo      = (const float*)d_in[7];
    const float* Wd      = (const float*)d_in[8];
    const float* bd      = (const float*)d_in[9];
    float* out = (float*)d_out;

    fused_kernel<<<dim3(B_ / 2), dim3(512), 0, stream>>>(
        x, lengths, Wi, Ui, bi, Wo, Uo, bo, Wd, bd, out);
}

// Round 16
// 180.689 us; speedup vs baseline: 1.1802x; 1.1802x over previous
//
#include <hip/hip_runtime.h>

#define B_  256
#define T_  256
#define S_  20
#define U1  32
#define G1  128   // 4*U1
#define U2  24
#define G2  96    // 4*U2
#define NT  16    // 16-row t-tiles per sequence

typedef __attribute__((ext_vector_type(8))) short short8;   // 8 bf16 = 4 VGPRs
typedef __attribute__((ext_vector_type(4))) float f32x4;    // MFMA acc

#define L2E  1.44269504f
// Raw-HW activations (v_exp_f32 = 2^x). R7: ocml->raw took outer 134->74us.
__device__ __forceinline__ float sigmoidf_(float x) {
    return __builtin_amdgcn_rcpf(1.0f + __builtin_amdgcn_exp2f(x * -L2E));
}
__device__ __forceinline__ float tanhf_fast(float x) {   // 1 - 2/(1+e^{2x})
    return 1.0f - 2.0f * __builtin_amdgcn_rcpf(1.0f + __builtin_amdgcn_exp2f(x * 2.0f * L2E));
}

__device__ __forceinline__ unsigned short f2bf(float a) {
    unsigned int u = __float_as_uint(a);
    u += 0x7FFFu + ((u >> 16) & 1u);
    return (unsigned short)(u >> 16);
}
__device__ __forceinline__ unsigned int pack2bf(float a, float b) {
    unsigned int ua = __float_as_uint(a); ua += 0x7FFFu + ((ua >> 16) & 1u);
    unsigned int ub = __float_as_uint(b); ub += 0x7FFFu + ((ub >> 16) & 1u);
    return (ua >> 16) | (ub & 0xFFFF0000u);
}
union frag_u { short8 v; unsigned int u[4]; };
union h2x  { unsigned int u32; _Float16 h[2]; };

// FUSED producer-consumer, R13 topology (256 thr = 4 waves, 1 wave/EU) with:
//  (a) cooperative tile 0: all 4 waves produce it together (wave w does the
//      activation work of C-reg r=w -> trans/4), double-buffered h, one
//      __syncthreads/step -> startup ~11us -> ~3.5us;
//  (b) lean consumer: half-split 48 FMA + 1 ds_read_b32 + 24 readlane, and
//      ACTIVATION-LOCAL gating: per-lane constants make sigmoid/tanh one
//      uniform code path (tanh = 2*sig(2x)-1), activations computed BEFORE
//      the cross-half shfl -> 2 trans/lane (was 4) and i*g needs no selects.
__global__ __attribute__((amdgpu_flat_work_group_size(256, 256)))
__attribute__((amdgpu_waves_per_eu(1, 1)))
void fused_kernel(
    const float* __restrict__ x,        // [B*T*S]
    const int*   __restrict__ lengths,  // [B]
    const float* __restrict__ Wi,       // [G1]
    const float* __restrict__ Ui,       // [U1*G1]
    const float* __restrict__ bi,       // [G1]
    const float* __restrict__ Wo,       // [U1*G2]
    const float* __restrict__ Uo,       // [U2*G2]
    const float* __restrict__ bo,       // [G2]
    const float* __restrict__ Wd,       // [U2]
    const float* __restrict__ bd,       // [1]
    float* __restrict__ out)            // [B]
{
    __shared__ __align__(16) _Float16      Pl[T_][G2];       // [t][u*4+g], 48 KB
    __shared__ __align__(16) unsigned short hb2[2][16][40];  // coop tile-0 h (dbuf)
    __shared__ __align__(16) unsigned short hbb[4][16][40];  // phase-B per-wave h
    __shared__ unsigned int flags[NT];
    const int b    = blockIdx.x;
    const int len  = lengths[b];                 // >= 1
    const int tid  = threadIdx.x;
    const int w    = __builtin_amdgcn_readfirstlane(tid >> 6);   // wave 0..3
    const int lane = tid & 63;
    const int q    = lane >> 4;
    const int n    = lane & 15;

    if (tid < NT) flags[tid] = 0;

    // ---- one-time fragment/bias loads (all waves) ----
    frag_u Bui[8];
#pragma unroll
    for (int tt = 0; tt < 8; ++tt)
#pragma unroll
        for (int k2 = 0; k2 < 4; ++k2)
            Bui[tt].u[k2] = pack2bf(Ui[(8 * q + 2 * k2) * G1 + 16 * tt + n],
                                    Ui[(8 * q + 2 * k2 + 1) * G1 + 16 * tt + n]);
    frag_u Bwo[6];
#pragma unroll
    for (int tt = 0; tt < 6; ++tt)
#pragma unroll
        for (int k2 = 0; k2 < 4; ++k2)
            Bwo[tt].u[k2] = pack2bf(Wo[(8 * q + 2 * k2) * G2 + 16 * tt + n],
                                    Wo[(8 * q + 2 * k2 + 1) * G2 + 16 * tt + n]);
    float bi_l[8], Wi_l[8], bo_l[6];
#pragma unroll
    for (int tt = 0; tt < 8; ++tt) { bi_l[tt] = bi[16 * tt + n]; Wi_l[tt] = Wi[16 * tt + n]; }
#pragma unroll
    for (int tt = 0; tt < 6; ++tt) bo_l[tt] = bo[16 * tt + n];
    int pcol[6];                                 // P col -> unit-major offset
#pragma unroll
    for (int tt = 0; tt < 6; ++tt) {
        const int col = 16 * tt + n;
        const int g = col / 24;
        pcol[tt] = (col - 24 * g) * 4 + g;
    }
    __syncthreads();                             // flags + before coop tile 0

    // ============ phase A: COOPERATIVE tile 0 (all 4 waves) ================
    {
        const int rw = w;                        // this wave's C-reg / row slot
        const float* xr = x + (size_t)(b * T_ + 4 * q) * S_;   // quad rows 4q..4q+3
        float c2[2] = { 0.0f, 0.0f };

        float xc[4];
#pragma unroll
        for (int r = 0; r < 4; ++r) xc[r] = xr[r * S_];

#pragma unroll 1
        for (int s = 0; s < S_; ++s) {
            const int sn = (s + 1 < S_) ? s + 1 : S_ - 1;
            float xnx[4];
#pragma unroll
            for (int r = 0; r < 4; ++r) xnx[r] = xr[r * S_ + sn];

            f32x4 acc[8];
#pragma unroll
            for (int tt = 0; tt < 8; ++tt)
#pragma unroll
                for (int r = 0; r < 4; ++r)
                    acc[tt][r] = bi_l[tt] + xc[r] * Wi_l[tt];

            if (s > 0) {                         // h==0 at s==0
                const short8 A = *(const short8*)&hb2[(s + 1) & 1][n][8 * q];
#pragma unroll
                for (int tt = 0; tt < 8; ++tt)
                    acc[tt] = __builtin_amdgcn_mfma_f32_16x16x32_bf16(A, Bui[tt].v, acc[tt], 0, 0, 0);
            }

            // activations: ONLY reg rw (this wave's rows {4q+rw})
            float zz[8];
#pragma unroll
            for (int tt = 0; tt < 8; ++tt) zz[tt] = acc[tt][rw];  // uniform sel
#pragma unroll
            for (int uh = 0; uh < 2; ++uh) {
                const float iv = sigmoidf_(zz[0 + uh]);
                const float fv = sigmoidf_(zz[2 + uh]);
                const float gv = tanhf_fast(zz[4 + uh]);
                const float ov = sigmoidf_(zz[6 + uh]);
                c2[uh] = fv * c2[uh] + iv * gv;
                hb2[s & 1][4 * q + rw][n + 16 * uh] = f2bf(ov * tanhf_fast(c2[uh]));
            }
            __syncthreads();                     // all 4 waves in phase A
#pragma unroll
            for (int r = 0; r < 4; ++r) xc[r] = xnx[r];
        }

        // P tile 0 = bo + h @ Wo; wave w writes its rows {4q+rw}
        {
            const short8 A = *(const short8*)&hb2[(S_ - 1) & 1][n][8 * q];
            f32x4 accp[6];
#pragma unroll
            for (int tt = 0; tt < 6; ++tt) {
#pragma unroll
                for (int r = 0; r < 4; ++r) accp[tt][r] = bo_l[tt];
                accp[tt] = __builtin_amdgcn_mfma_f32_16x16x32_bf16(A, Bwo[tt].v, accp[tt], 0, 0, 0);
            }
            const int tr = 4 * q + rw;
#pragma unroll
            for (int tt = 0; tt < 6; ++tt)
                Pl[tr][pcol[tt]] = (_Float16)accp[tt][rw];
        }
        __syncthreads();                         // tile 0 visible to consumer
    }

    // ============ phase B: waves 1-3 produce tiles 1..15 ===================
    if (w != 0) {
#pragma unroll 1
        for (int i = 0; i < 5; ++i) {
            const int tile = w + 3 * i;          // {1,4,..},{2,5,..},{3,6,..}
            const int wt0  = tile * 16;
            if (wt0 >= len) break;               // increasing: rest masked too

            const float* xr = x + (size_t)(b * T_ + wt0 + 4 * q) * S_;
            float c[2][4];
#pragma unroll
            for (int uh = 0; uh < 2; ++uh)
#pragma unroll
                for (int r = 0; r < 4; ++r) c[uh][r] = 0.0f;

            float xc[4];
#pragma unroll
            for (int r = 0; r < 4; ++r) xc[r] = xr[r * S_];

#pragma unroll 1
            for (int s = 0; s < S_; ++s) {
                const int sn = (s + 1 < S_) ? s + 1 : S_ - 1;
                float xnx[4];
#pragma unroll
                for (int r = 0; r < 4; ++r) xnx[r] = xr[r * S_ + sn];

                f32x4 acc[8];
#pragma unroll
                for (int tt = 0; tt < 8; ++tt)
#pragma unroll
                    for (int r = 0; r < 4; ++r)
                        acc[tt][r] = bi_l[tt] + xc[r] * Wi_l[tt];

                if (s > 0) {
                    const short8 A = *(const short8*)&hbb[w][n][8 * q];
#pragma unroll
                    for (int tt = 0; tt < 8; ++tt)
                        acc[tt] = __builtin_amdgcn_mfma_f32_16x16x32_bf16(A, Bui[tt].v, acc[tt], 0, 0, 0);
                }
#pragma unroll
                for (int uh = 0; uh < 2; ++uh)
#pragma unroll
                    for (int r = 0; r < 4; ++r) {
                        const float iv = sigmoidf_(acc[0 + uh][r]);
                        const float fv = sigmoidf_(acc[2 + uh][r]);
                        const float gv = tanhf_fast(acc[4 + uh][r]);
                        const float ov = sigmoidf_(acc[6 + uh][r]);
                        c[uh][r] = fv * c[uh][r] + iv * gv;
                        hbb[w][4 * q + r][n + 16 * uh] = f2bf(ov * tanhf_fast(c[uh][r]));
                    }
#pragma unroll
                for (int r = 0; r < 4; ++r) xc[r] = xnx[r];
            }

            {   // P tile -> LDS unit-major
                const short8 A = *(const short8*)&hbb[w][n][8 * q];
                f32x4 accp[6];
#pragma unroll
                for (int tt = 0; tt < 6; ++tt) {
#pragma unroll
                    for (int r = 0; r < 4; ++r) accp[tt][r] = bo_l[tt];
                    accp[tt] = __builtin_amdgcn_mfma_f32_16x16x32_bf16(A, Bwo[tt].v, accp[tt], 0, 0, 0);
                }
#pragma unroll
                for (int r = 0; r < 4; ++r) {
                    const int tr = wt0 + 4 * q + r;
#pragma unroll
                    for (int tt = 0; tt < 6; ++tt)
                        Pl[tr][pcol[tt]] = (_Float16)accp[tt][r];
                }
            }
            __hip_atomic_store(&flags[tile], 1u, __ATOMIC_RELEASE,
                               __HIP_MEMORY_SCOPE_WORKGROUP);
        }
        return;                                  // producers retire
    }

    // ============ consumer: outer LSTM + head (wave 0) =====================
    const int half = lane >> 5;                  // 0: gates i,f  1: gates g,o
    const int sub  = lane & 31;
    const int u    = (sub < U2) ? sub : U2 - 1;

    float wA[U2], wB[U2];                        // 48 weight VGPRs, resident
#pragma unroll
    for (int k = 0; k < U2; ++k) {
        wA[k] = Uo[k * G2 + (2 * half) * U2 + u];
        wB[k] = Uo[k * G2 + (2 * half + 1) * U2 + u];
    }
    // activation-local constants: half0 actA = sigmoid (zA = z_i);
    // half1 actA = tanh (zA = z_g) = 2*sig(2x)-1. actB always sigmoid.
    const float mA = half ? (-2.0f * L2E) : (-L2E);
    const float sA = half ? 2.0f : 1.0f;
    const float tA = half ? -1.0f : 0.0f;

    // one ds_read_b32 per step: my 2 gates of unit u (f16 pair)
    auto ld2 = [&](int t) -> float2 {
        h2x pp; pp.u32 = *reinterpret_cast<const unsigned int*>(&Pl[t][4 * u + 2 * half]);
        return make_float2((float)pp.h[0], (float)pp.h[1]);
    };

    float cu, hu;
    {   // peeled t = 0 (h == 0, c == 0)
        const float2 r0 = ld2(0);
        const float actA = sA * __builtin_amdgcn_rcpf(1.0f + __builtin_amdgcn_exp2f(r0.x * mA)) + tA;
        const float actB = sigmoidf_(r0.y);
        const float xA = __shfl_xor(actA, 32);   // other half's actA
        const float xB = __shfl_xor(actB, 32);
        const float ov = half ? actB : xB;       // sigma(z_o)
        cu = actA * xA;                          // i*g on both halves
        hu = ov * tanhf_fast(cu);
    }

    int t = 1, tile = 0;
    int tend = (16 < len) ? 16 : len;
    float2 nxt = ld2((1 < len) ? 1 : 0);

#pragma unroll 1
    while (t < len) {
#pragma unroll 1
        for (; t + 1 < tend; ++t) {              // hot loop, in-tile prefetch
            const float2 pf = ld2(t + 1);

            float hk[U2];
#pragma unroll
            for (int k = 0; k < U2; ++k)
                hk[k] = __int_as_float(__builtin_amdgcn_readlane(__float_as_int(hu), k));

            float a0 = nxt.x, a1 = 0.0f, b0 = nxt.y, b1 = 0.0f;
#pragma unroll
            for (int k = 0; k < U2; k += 2) {    // 2+2 chains, depth 12
                a0 += hk[k]     * wA[k];     b0 += hk[k]     * wB[k];
                a1 += hk[k + 1] * wA[k + 1]; b1 += hk[k + 1] * wB[k + 1];
            }
            const float zA = a0 + a1;            // half0: z_i ; half1: z_g
            const float zB = b0 + b1;            // half0: z_f ; half1: z_o

            // activations BEFORE swap (2 trans/lane)
            const float actA = sA * __builtin_amdgcn_rcpf(1.0f + __builtin_amdgcn_exp2f(zA * mA)) + tA;
            const float actB = sigmoidf_(zB);
            const float xA = __shfl_xor(actA, 32);
            const float xB = __shfl_xor(actB, 32);

            const float fv = half ? xB : actB;   // sigma(z_f)
            const float ov = half ? actB : xB;   // sigma(z_o)
            cu = fv * cu + actA * xA;            // i*g select-free
            hu = ov * tanhf_fast(cu);            // identical on both halves
            nxt = pf;
        }

        // boundary row t == tend-1: flag-wait + next tile's first row
        float2 pf = nxt;
        if (tend < len) {                        // wave-uniform
            ++tile;
            while (__hip_atomic_load(&flags[tile], __ATOMIC_ACQUIRE,
                                     __HIP_MEMORY_SCOPE_WORKGROUP) == 0u)
                __builtin_amdgcn_s_sleep(1);
            pf = ld2(tend);
        }
        {
            float hk[U2];
#pragma unroll
            for (int k = 0; k < U2; ++k)
                hk[k] = __int_as_float(__builtin_amdgcn_readlane(__float_as_int(hu), k));

            float a0 = nxt.x, a1 = 0.0f, b0 = nxt.y, b1 = 0.0f;
#pragma unroll
            for (int k = 0; k < U2; k += 2) {
                a0 += hk[k]     * wA[k];     b0 += hk[k]     * wB[k];
                a1 += hk[k + 1] * wA[k + 1]; b1 += hk[k + 1] * wB[k + 1];
            }
            const float zA = a0 + a1;
            const float zB = b0 + b1;
            const float actA = sA * __builtin_amdgcn_rcpf(1.0f + __builtin_amdgcn_exp2f(zA * mA)) + tA;
            const float actB = sigmoidf_(zB);
            const float xA = __shfl_xor(actA, 32);
            const float xB = __shfl_xor(actB, 32);
            const float fv = half ? xB : actB;
            const float ov = half ? actB : xB;
            cu = fv * cu + actA * xA;
            hu = ov * tanhf_fast(cu);
        }
        ++t;
        nxt = pf;
        tend = (tend + 16 < len) ? tend + 16 : len;
    }

    // dense sigmoid head
    float acc = bd[0];
#pragma unroll
    for (int k = 0; k < U2; ++k)
        acc += __int_as_float(__builtin_amdgcn_readlane(__float_as_int(hu), k)) * Wd[k];
    if (lane == 0) out[b] = sigmoidf_(acc);
}

extern "C" void kernel_launch(void* const* d_in, const int* in_sizes, int n_in,
                              void* d_out, int out_size, void* d_ws, size_t ws_size,
                              hipStream_t stream) {
    const float* x       = (const float*)d_in[0];
    const int*   lengths = (const int*)  d_in[1];
    const float* Wi      = (const float*)d_in[2];
    const float* Ui      = (const float*)d_in[3];
    const float* bi      = (const float*)d_in[4];
    const float* Wo      = (const float*)d_in[5];
    const float* Uo      = (const float*)d_in[6];
    const float* bo      = (const float*)d_in[7];
    const float* Wd      = (const float*)d_in[8];
    const float* bd      = (const float*)d_in[9];
    float* out = (float*)d_out;

    fused_kernel<<<dim3(B_), dim3(256), 0, stream>>>(
        x, lengths, Wi, Ui, bi, Wo, Uo, bo, Wd, bd, out);
}